// Round 11
// baseline (478.808 us; speedup 1.0000x reference)
//
#include <hip/hip_runtime.h>
#include <hip/hip_bf16.h>
#include <math.h>
#include <stdint.h>

// ---- problem constants ----
#define B_    4
#define S_    2048
#define D_    768
#define H_    8
#define HD_   96
#define EXPD_ 3072
#define MSZ   8192   // B*S

#define QSCALE 0.14724439f   // HD^-0.5 * log2(e), folded into Q at QKV epilogue
#define M0_    12.0f         // fixed softmax exponent offset

typedef __bf16 bf16;
typedef __bf16 bf16x4 __attribute__((ext_vector_type(4)));
typedef __bf16 bf16x8 __attribute__((ext_vector_type(8)));
typedef float  f32x4  __attribute__((ext_vector_type(4)));
typedef float  f32x16 __attribute__((ext_vector_type(16)));

typedef __attribute__((address_space(1))) const uint32_t gu32;
typedef __attribute__((address_space(3))) uint32_t lu32;

__device__ __forceinline__ void async_copy16(const void* g, void* l) {
    __builtin_amdgcn_global_load_lds((gu32*)g, (lu32*)l, 16, 0, 0);
}

__device__ __forceinline__ float gelu_f(float x) {
    float x3 = x * x * x;
    return 0.5f * x * (1.0f + tanhf(0.7978845608028654f * (x + 0.044715f * x3)));
}

// Runtime dtype sniff: f32 buffer read as bf16 at even indices yields random
// exponents -> some |v|>=1e3 among 64 samples w.p. ~1. bf16 weights never trip.
__device__ __forceinline__ bool sniff_f32(const void* p) {
    const bf16* pb = (const bf16*)p;
    float v = (float)pb[2 * (threadIdx.x & 63)];
    bool big = !(fabsf(v) < 1000.0f);
    return __any(big) != 0;
}

__device__ __forceinline__ float dynld(const void* p, size_t i, bool f32in) {
    return f32in ? ((const float*)p)[i] : (float)((const bf16*)p)[i];
}

// Cast src (sniffed f32/bf16) -> bf16, 8 el/thread.
__global__ __launch_bounds__(256) void cast_kernel(
    const void* __restrict__ src, bf16* __restrict__ dst)
{
    const bool f32in = sniff_f32(src);
    size_t i = ((size_t)blockIdx.x * 256 + threadIdx.x) * 8;
    if (f32in) {
        f32x4 a = *(const f32x4*)((const float*)src + i);
        f32x4 b = *(const f32x4*)((const float*)src + i + 4);
        bf16x8 r;
#pragma unroll
        for (int e = 0; e < 4; ++e) { r[e] = (bf16)a[e]; r[e + 4] = (bf16)b[e]; }
        *(bf16x8*)(dst + i) = r;
    } else {
        *(bf16x8*)(dst + i) = *(const bf16x8*)((const bf16*)src + i);
    }
}

#define MODE_QKV  0   // fused QKV: Q(*QSCALE),K -> [bh][S][HD]; V -> [bh][HD][S]
#define MODE_RES  1   // out bf16 = c + bias(if boff>=0) + res
#define MODE_GELU 2   // out bf16 = gelu(c + bias)

// 32x32x16-MFMA GEMM: C = A(MxK, row-stride lda) @ Bt(NxK, row-stride ldb)^T
// + bias[boff+n] (boff<0: none). Tile 128xBN, BK=32, 4 waves,
// global_load_lds width-16 staging, stride-32 LDS.
// 1-D grid, XCD-aware decode: xcd = lin&7 owns m-stripe xcd (mstripe 128-row
// blocks), m varies FASTEST within the stripe -> the stripe's A panel stays
// L2-resident across all N-columns; B columns read ~once per XCD.
template<int MODE, bool ADYN, bool RESDYN, int BN>
__global__ __launch_bounds__(256) void gemm2_kernel(
    const void* __restrict__ A, const bf16* __restrict__ Bt,
    const void* __restrict__ b0, const void* __restrict__ b1, const void* __restrict__ b2,
    const void* __restrict__ res, bf16* __restrict__ out,
    int M, int N, int K, int lda, int ldb, int boff, int mstripe,
    const void* __restrict__ sniffp)
{
    constexpr int WN   = BN / 2;
    constexpr int NJ32 = WN / 32;
    __shared__ __align__(16) bf16 Sh[8192];   // As | Bs in k-loop; C-stage in epilogue
    bf16* As = Sh;
    bf16* Bs = Sh + 4096;

    const bool f32in = sniff_f32(sniffp);
    const int tid  = threadIdx.x;
    const int w    = tid >> 6;
    const int lane = tid & 63;
    const int l32  = lane & 31;
    const int kh   = lane >> 5;     // k-half for A/B frags
    const int wr   = w >> 1, wc = w & 1;

    // XCD-aware block decode (m-fast within stripe)
    const int lin  = blockIdx.x;
    const int xcd  = lin & 7;
    const int q    = lin >> 3;
    const int nb   = q / mstripe;
    const int mbin = q - nb * mstripe;
    const int m0   = (xcd * mstripe + mbin) * 128;
    const int n0   = nb * BN;

    const int rsub = lane >> 2;
    const int cb8  = (lane & 3) * 8;

    f32x16 acc[2][NJ32];
#pragma unroll
    for (int i = 0; i < 2; ++i)
#pragma unroll
        for (int j = 0; j < NJ32; ++j)
#pragma unroll
            for (int e = 0; e < 16; ++e) acc[i][j][e] = 0.f;

    const bf16*  Abf = (const bf16*)A;
    const float* Af  = (const float*)A;

    for (int k0 = 0; k0 < K; k0 += 32) {
        __syncthreads();
        if (ADYN && f32in) {
#pragma unroll
            for (int a = 0; a < 2; ++a) {
                int row = w * 32 + a * 16 + rsub;
                const float* sp = Af + (size_t)(m0 + row) * lda + k0 + cb8;
                f32x4 u0 = *(const f32x4*)sp;
                f32x4 u1 = *(const f32x4*)(sp + 4);
                bf16x8 v;
#pragma unroll
                for (int e = 0; e < 4; ++e) { v[e] = (bf16)u0[e]; v[e + 4] = (bf16)u1[e]; }
                *(bf16x8*)(&As[(size_t)(w * 32 + a * 16) * 32 + lane * 8]) = v;
            }
        } else {
#pragma unroll
            for (int a = 0; a < 2; ++a) {
                int row = w * 32 + a * 16 + rsub;
                async_copy16(Abf + (size_t)(m0 + row) * lda + k0 + cb8,
                             &As[(w * 32 + a * 16) * 32]);
            }
        }
#pragma unroll
        for (int a = 0; a < BN / 64; ++a) {
            int row = w * (BN / 4) + a * 16 + rsub;
            async_copy16(Bt + (size_t)(n0 + row) * ldb + k0 + cb8,
                         &Bs[(w * (BN / 4) + a * 16) * 32]);
        }
        __syncthreads();

        bf16x8 af[2][2], bfv[NJ32][2];
#pragma unroll
        for (int i = 0; i < 2; ++i)
#pragma unroll
            for (int ks = 0; ks < 2; ++ks)
                af[i][ks] = *(const bf16x8*)(&As[(wr * 64 + i * 32 + l32) * 32 + ks * 16 + kh * 8]);
#pragma unroll
        for (int j = 0; j < NJ32; ++j)
#pragma unroll
            for (int ks = 0; ks < 2; ++ks)
                bfv[j][ks] = *(const bf16x8*)(&Bs[(wc * WN + j * 32 + l32) * 32 + ks * 16 + kh * 8]);
#pragma unroll
        for (int i = 0; i < 2; ++i)
#pragma unroll
            for (int j = 0; j < NJ32; ++j)
#pragma unroll
                for (int ks = 0; ks < 2; ++ks)
                    acc[i][j] = __builtin_amdgcn_mfma_f32_32x32x16_bf16(af[i][ks], bfv[j][ks], acc[i][j], 0, 0, 0);
    }

    if constexpr (MODE == MODE_QKV) {
        // scatter epilogue (scalar; layout non-contiguous by design)
#pragma unroll
        for (int j = 0; j < NJ32; ++j) {
            int nbase = n0 + wc * WN + j * 32;      // multiple of 32
            int which = nbase / D_;                 // wave-uniform
            int n2b   = nbase - which * D_;
            int h     = n2b / HD_;                  // wave-uniform (32 | 96)
            int hd0   = n2b - h * HD_;
            const void* bp = which == 0 ? b0 : (which == 1 ? b1 : b2);
            float bval = dynld(bp, n2b + l32, f32in);
            int hd = hd0 + l32;
#pragma unroll
            for (int i = 0; i < 2; ++i) {
#pragma unroll
                for (int g = 0; g < 16; ++g) {
                    int rr = (g & 3) + 8 * (g >> 2) + 4 * kh;
                    int m  = m0 + wr * 64 + i * 32 + rr;
                    float v = acc[i][j][g] + bval;
                    int b  = m >> 11;
                    int ss = m & (S_ - 1);
                    int bh = b * H_ + h;
                    if (which == 0) v *= QSCALE;
                    size_t dst;
                    if (which < 2)
                        dst = (size_t)which * (MSZ * D_) + ((size_t)bh * S_ + ss) * HD_ + hd;
                    else
                        dst = (size_t)2 * (MSZ * D_) + ((size_t)bh * HD_ + hd) * S_ + ss;
                    out[dst] = (bf16)v;
                }
            }
        }
    } else {
        // dense epilogue: stage C through LDS, emit b128 loads/stores.
        __syncthreads();                 // all waves done reading As/Bs
        bf16* Cw = Sh + w * 2048;        // per-wave 64 x 32 slice
        for (int j = 0; j < NJ32; ++j) {
            int nl = n0 + wc * WN + j * 32 + l32;
            float bval = boff >= 0 ? dynld(b0, boff + nl, f32in) : 0.f;
#pragma unroll
            for (int i = 0; i < 2; ++i)
#pragma unroll
                for (int g = 0; g < 16; ++g) {
                    int rr = (g & 3) + 8 * (g >> 2) + 4 * kh;
                    float v = acc[i][j][g] + bval;
                    if constexpr (MODE == MODE_GELU) v = gelu_f(v);
                    Cw[(i * 32 + rr) * 32 + l32] = (bf16)v;
                }
            // same-wave LDS ops are in-order: reads below see the writes above
#pragma unroll
            for (int pass = 0; pass < 4; ++pass) {
                int row = pass * 16 + (lane >> 2);
                int cc  = (lane & 3) * 8;
                bf16x8 cv = *(const bf16x8*)&Cw[row * 32 + cc];
                int m = m0 + wr * 64 + row;
                int n = n0 + wc * WN + j * 32 + cc;
                size_t off = (size_t)m * N + n;
                if constexpr (MODE == MODE_RES) {
                    bf16x8 o;
                    if (RESDYN && f32in) {
                        f32x4 r0 = *(const f32x4*)((const float*)res + off);
                        f32x4 r1 = *(const f32x4*)((const float*)res + off + 4);
#pragma unroll
                        for (int e = 0; e < 4; ++e) {
                            o[e]     = (bf16)((float)cv[e] + r0[e]);
                            o[e + 4] = (bf16)((float)cv[e + 4] + r1[e]);
                        }
                    } else {
                        bf16x8 rv = *(const bf16x8*)((const bf16*)res + off);
#pragma unroll
                        for (int e = 0; e < 8; ++e) o[e] = (bf16)((float)cv[e] + (float)rv[e]);
                    }
                    *(bf16x8*)&out[off] = o;
                } else {
                    *(bf16x8*)&out[off] = cv;
                }
            }
        }
    }
}

// Flash attention: 512 threads (8 waves), Q-tile 128 (16 q-rows/wave),
// KV-tile 64, fixed-max softmax. Q,K: [bh][S][96]; Vt_g: [bh][96][S].
// grid (B*H, S/128): x = bh -> XCD k owns bh === k (mod 8) -> K/V L2 locality.
__global__ __launch_bounds__(512, 6) void flash_kernel(
    const bf16* __restrict__ Q, const bf16* __restrict__ Kk,
    const bf16* __restrict__ Vt_g, bf16* __restrict__ ctx)
{
    __shared__ __align__(16) bf16 Ks[64][104];
    __shared__ __align__(16) bf16 Vs[96][72];
    __shared__ __align__(16) bf16 Ps[8][16][72];  // per-wave P [q][kv]

    const int tid  = threadIdx.x;
    const int w    = tid >> 6;
    const int lane = tid & 63;
    const int quad = lane >> 4;
    const int l16  = lane & 15;
    const int bh   = blockIdx.x;
    const size_t base = (size_t)bh * S_ * HD_;
    const int q0   = blockIdx.y * 128 + w * 16;

    bf16x8 qf[3];
#pragma unroll
    for (int ch = 0; ch < 3; ++ch)
        qf[ch] = *(const bf16x8*)(Q + base + (size_t)(q0 + l16) * HD_ + ch * 32 + quad * 8);

    f32x4 oacc[6];
#pragma unroll
    for (int c = 0; c < 6; ++c) oacc[c] = (f32x4){0.f, 0.f, 0.f, 0.f};
    float lsum[4] = {0.f, 0.f, 0.f, 0.f};

    // division-free staging maps (512 threads)
    const int kvi  = tid & 255;
    const int ch2  = tid >> 8;                 // 0,1
    const int krow = kvi >> 2, kc8 = (kvi & 3) * 8 + ch2 * 32;
    const int vrow = (kvi >> 3) + ch2 * 32, vcb = (kvi & 7) * 8;
    const int krow2 = tid >> 2, kc82 = (tid & 3) * 8 + 64;   // tid<256
    const int vrow2 = (tid >> 3) + 64, vcb2 = (tid & 7) * 8; // tid<256

    for (int kv0 = 0; kv0 < S_; kv0 += 64) {
        __syncthreads();
        *(bf16x8*)(&Ks[krow][kc8]) =
            *(const bf16x8*)(Kk + base + (size_t)(kv0 + krow) * HD_ + kc8);
        *(bf16x8*)(&Vs[vrow][vcb]) =
            *(const bf16x8*)(Vt_g + base + (size_t)vrow * S_ + kv0 + vcb);
        if (tid < 256) {
            *(bf16x8*)(&Ks[krow2][kc82]) =
                *(const bf16x8*)(Kk + base + (size_t)(kv0 + krow2) * HD_ + kc82);
            *(bf16x8*)(&Vs[vrow2][vcb2]) =
                *(const bf16x8*)(Vt_g + base + (size_t)vrow2 * S_ + kv0 + vcb2);
        }
        __syncthreads();

        // S = (Q*QSCALE) K^T : four 16x16 kv-tiles
        f32x4 sacc[4];
#pragma unroll
        for (int t = 0; t < 4; ++t) {
            sacc[t] = (f32x4){0.f, 0.f, 0.f, 0.f};
#pragma unroll
            for (int ch = 0; ch < 3; ++ch) {
                bf16x8 kf = *(const bf16x8*)(&Ks[t * 16 + l16][ch * 32 + quad * 8]);
                sacc[t] = __builtin_amdgcn_mfma_f32_16x16x32_bf16(qf[ch], kf, sacc[t], 0, 0, 0);
            }
        }

        // fixed-max softmax: p = 2^(sacc - M0); per-lane partial row sums only
#pragma unroll
        for (int r = 0; r < 4; ++r) {
            int qr = quad * 4 + r;
            float p0 = exp2f(sacc[0][r] - M0_);
            float p1 = exp2f(sacc[1][r] - M0_);
            float p2 = exp2f(sacc[2][r] - M0_);
            float p3 = exp2f(sacc[3][r] - M0_);
            lsum[r] += (p0 + p1) + (p2 + p3);
            Ps[w][qr][l16]      = (bf16)p0;
            Ps[w][qr][16 + l16] = (bf16)p1;
            Ps[w][qr][32 + l16] = (bf16)p2;
            Ps[w][qr][48 + l16] = (bf16)p3;
        }
        // no barrier: Ps is per-wave (in-wave lgkmcnt ordering suffices)

        bf16x8 pf0 = *(const bf16x8*)(&Ps[w][l16][quad * 8]);
        bf16x8 pf1 = *(const bf16x8*)(&Ps[w][l16][32 + quad * 8]);
#pragma unroll
        for (int c = 0; c < 6; ++c) {
            bf16x8 vf0 = *(const bf16x8*)(&Vs[c * 16 + l16][quad * 8]);
            bf16x8 vf1 = *(const bf16x8*)(&Vs[c * 16 + l16][32 + quad * 8]);
            oacc[c] = __builtin_amdgcn_mfma_f32_16x16x32_bf16(pf0, vf0, oacc[c], 0, 0, 0);
            oacc[c] = __builtin_amdgcn_mfma_f32_16x16x32_bf16(pf1, vf1, oacc[c], 0, 0, 0);
        }
    }

#pragma unroll
    for (int r = 0; r < 4; ++r)
#pragma unroll
        for (int off = 1; off < 16; off <<= 1)
            lsum[r] += __shfl_xor(lsum[r], off);

    const int b = bh >> 3, h = bh & 7;
#pragma unroll
    for (int r = 0; r < 4; ++r) {
        float inv = 1.0f / lsum[r];
        int srow = q0 + quad * 4 + r;
        size_t rowbase = ((size_t)b * S_ + srow) * D_ + h * HD_;
#pragma unroll
        for (int c = 0; c < 6; ++c)
            ctx[rowbase + c * 16 + l16] = (bf16)(oacc[c][r] * inv);
    }
}

// LayerNorm over D=768: one wave per row (12 el/lane, bf16x4 vector I/O).
template<bool OUTDYN>
__global__ __launch_bounds__(256) void ln_kernel(
    const bf16* __restrict__ in, const void* __restrict__ g, const void* __restrict__ be,
    void* __restrict__ out, const void* __restrict__ sniffp)
{
    const bool f32in = sniff_f32(sniffp);
    const int w = threadIdx.x >> 6, lane = threadIdx.x & 63;
    const int row = blockIdx.x * 4 + w;
    const size_t rbase = (size_t)row * D_ + lane * 12;

    float v[12];
#pragma unroll
    for (int j = 0; j < 3; ++j) {
        bf16x4 t = *(const bf16x4*)(in + rbase + j * 4);
#pragma unroll
        for (int e = 0; e < 4; ++e) v[j * 4 + e] = (float)t[e];
    }
    float sum = 0.f;
#pragma unroll
    for (int j = 0; j < 12; ++j) sum += v[j];
#pragma unroll
    for (int off = 1; off < 64; off <<= 1) sum += __shfl_xor(sum, off);
    float mu = sum * (1.0f / D_);
    float sq = 0.f;
#pragma unroll
    for (int j = 0; j < 12; ++j) { v[j] -= mu; sq += v[j] * v[j]; }
#pragma unroll
    for (int off = 1; off < 64; off <<= 1) sq += __shfl_xor(sq, off);
    float rstd = rsqrtf(sq * (1.0f / D_) + 1e-5f);

    if (OUTDYN && f32in) {
        float* op = (float*)out + rbase;
#pragma unroll
        for (int j = 0; j < 3; ++j) {
            f32x4 t;
#pragma unroll
            for (int e = 0; e < 4; ++e) {
                int c = lane * 12 + j * 4 + e;
                t[e] = v[j * 4 + e] * rstd * dynld(g, c, true) + dynld(be, c, true);
            }
            *(f32x4*)(op + j * 4) = t;
        }
    } else {
        bf16* op = (bf16*)out + rbase;
#pragma unroll
        for (int j = 0; j < 3; ++j) {
            bf16x4 t;
#pragma unroll
            for (int e = 0; e < 4; ++e) {
                int c = lane * 12 + j * 4 + e;
                t[e] = (bf16)(v[j * 4 + e] * rstd * dynld(g, c, f32in) + dynld(be, c, f32in));
            }
            *(bf16x4*)(op + j * 4) = t;
        }
    }
}

// Transpose 64x64 tile helper
__device__ __forceinline__ void transpose_tile(
    const void* __restrict__ src, bf16* __restrict__ dst, int R, int C,
    int r0, int c0, bool f32in)
{
    __shared__ bf16 t[64][65];
    const int tx = threadIdx.x & 63, ty = threadIdx.x >> 6;
#pragma unroll
    for (int i = 0; i < 16; ++i) {
        int rr = ty + i * 4;
        t[rr][tx] = (bf16)dynld(src, (size_t)(r0 + rr) * C + c0 + tx, f32in);
    }
    __syncthreads();
#pragma unroll
    for (int i = 0; i < 16; ++i) {
        int cc = ty + i * 4;
        dst[(size_t)(c0 + cc) * R + r0 + tx] = t[tx][cc];
    }
}

// Wq/Wk/Wv (all 768x768) -> dst + z*D*D, one launch, grid (12,12,3)
__global__ __launch_bounds__(256) void transpose_qkv_kernel(
    const void* __restrict__ s0, const void* __restrict__ s1, const void* __restrict__ s2,
    bf16* __restrict__ dst)
{
    const void* src = blockIdx.z == 0 ? s0 : (blockIdx.z == 1 ? s1 : s2);
    const bool f32in = sniff_f32(src);
    transpose_tile(src, dst + (size_t)blockIdx.z * D_ * D_, D_, D_,
                   blockIdx.y * 64, blockIdx.x * 64, f32in);
}

// Wo/W1/W2 -> WoT|W1T|W2T, packed 1-D grid of 1296 tiles (no idle blocks)
__global__ __launch_bounds__(256) void transpose_mlp_kernel(
    const void* __restrict__ s0, const void* __restrict__ s1, const void* __restrict__ s2,
    bf16* __restrict__ dst)
{
    int id = blockIdx.x;
    const void* src;
    int R, C, r, c;
    size_t off;
    if (id < 144)      { src = s0; R = D_;    C = D_;    off = 0;
                         r = id / 12;          c = id % 12; }
    else if (id < 720) { src = s1; R = D_;    C = EXPD_; off = (size_t)D_ * D_;
                         int i = id - 144;     r = i / 48; c = i % 48; }
    else               { src = s2; R = EXPD_; C = D_;    off = (size_t)D_ * D_ + (size_t)D_ * EXPD_;
                         int i = id - 720;     r = i / 12; c = i % 12; }
    const bool f32in = sniff_f32(src);
    transpose_tile(src, dst + off, R, C, r * 64, c * 64, f32in);
}

extern "C" void kernel_launch(void* const* d_in, const int* in_sizes, int n_in,
                              void* d_out, int out_size, void* d_ws, size_t ws_size,
                              hipStream_t stream)
{
    (void)in_sizes; (void)n_in; (void)out_size;
    const void* x   = d_in[0];
    const void* Wq  = d_in[1];
    const void* bq  = d_in[2];
    const void* Wk  = d_in[3];
    const void* bk  = d_in[4];
    const void* Wv  = d_in[5];
    const void* bv  = d_in[6];
    const void* Wo  = d_in[7];
    const void* bo  = d_in[8];
    const void* g1  = d_in[9];
    const void* be1 = d_in[10];
    const void* W1  = d_in[11];
    const void* bf1 = d_in[12];
    const void* W2  = d_in[13];
    const void* bf2 = d_in[14];
    const void* g2  = d_in[15];
    const void* be2 = d_in[16];

    const size_t REG = (size_t)MSZ * D_ * 2;  // 12.58 MB
    char* p = (char*)d_ws;
    bf16* R0 = (bf16*)p;             // Q     -> x1
    bf16* R1 = (bf16*)(p + REG);     // K     -> WoT|W1T|W2T (10.0 MB)
    bf16* R2 = (bf16*)(p + 2 * REG); // V^T   -> (nsplit: hb) / (tier0: y2)
    bf16* R3 = (bf16*)(p + 3 * REG); // y1    -> (tier3: y2) / (nsplit: hb hi) / (tier0: hb)
    bf16* R4 = (bf16*)(p + 4 * REG); // xb (tier>=1); nsplit: -> y2

    // tiers: 3 = 9 REG (full h at p+4..8, xb at p+8) | 1 = 5 REG (nsplit) | 0 = 4 REG
    int tier = 0;
    if      (ws_size >= 9 * REG) tier = 3;
    else if (ws_size >= 5 * REG) tier = 1;
    bf16* xb = tier == 3 ? (bf16*)(p + 8 * REG) : R4;

    bf16* qkvT = (bf16*)d_out;       // WqT|WkT|WvT (3.54 MB) before flash
    bf16* ctx  = (bf16*)d_out;
    dim3 blk(256);
    const int MB8 = MSZ / 128 / 8;   // mstripe for full-M GEMMs = 8

    // 0) cast x -> bf16
    if (tier >= 1) cast_kernel<<<dim3(MSZ * D_ / (256 * 8)), blk, 0, stream>>>(x, xb);

    // 1) transpose Wq/Wk/Wv -> qkvT [2304][768]
    transpose_qkv_kernel<<<dim3(12, 12, 3), blk, 0, stream>>>(Wq, Wk, Wv, qkvT);

    // 2) fused QKV GEMM -> Q*QSCALE(R0), K(R1), V^T(R2).  grid 64x18 = 1152
    if (tier >= 1)
        gemm2_kernel<MODE_QKV, false, false, 128><<<dim3(64 * 18), blk, 0, stream>>>(
            xb, qkvT, bq, bk, bv, nullptr, R0, MSZ, 2304, D_, D_, D_, 0, MB8, Wq);
    else
        gemm2_kernel<MODE_QKV, true, false, 128><<<dim3(64 * 18), blk, 0, stream>>>(
            x, qkvT, bq, bk, bv, nullptr, R0, MSZ, 2304, D_, D_, D_, 0, MB8, Wq);

    // 3) flash attention -> ctx (d_out; qkvT dead). grid x = bh (XCD locality).
    flash_kernel<<<dim3(B_ * H_, S_ / 128), dim3(512), 0, stream>>>(R0, R1, R2, ctx);

    // 4) transpose Wo/W1/W2 into R1 (K dead)
    bf16* WoT = R1;
    bf16* W1T = WoT + (size_t)D_ * D_;
    bf16* W2T = W1T + (size_t)D_ * EXPD_;
    transpose_mlp_kernel<<<dim3(1296), blk, 0, stream>>>(Wo, W1, W2, WoT);

    // 5) y1 = ctx@Wo + bo + x -> R3   (BN=64, grid 64x12 = 768)
    if (tier >= 1)
        gemm2_kernel<MODE_RES, false, false, 64><<<dim3(64 * 12), blk, 0, stream>>>(
            ctx, WoT, bo, nullptr, nullptr, xb, R3, MSZ, D_, D_, D_, D_, 0, MB8, Wq);
    else
        gemm2_kernel<MODE_RES, false, true, 64><<<dim3(64 * 12), blk, 0, stream>>>(
            ctx, WoT, bo, nullptr, nullptr, x, R3, MSZ, D_, D_, D_, D_, 0, MB8, Wq);

    // 6) x1 = LN1(y1) -> R0 (Q dead)
    bf16* x1b = R0;
    ln_kernel<false><<<dim3(MSZ / 4), blk, 0, stream>>>(R3, g1, be1, x1b, Wq);

    // 7/8) FFN -> y2
    bf16* y2b;
    if (tier == 3) {
        // full h (4 REG at p+4..8); W2 split over K (lda = EXPD_ -- h row stride!)
        bf16* hb = R4;
        y2b = R3;   // y1 dead
        gemm2_kernel<MODE_GELU, false, false, 128><<<dim3(64 * 24), blk, 0, stream>>>(
            x1b, W1T, bf1, nullptr, nullptr, nullptr, hb, MSZ, EXPD_, D_, D_, D_, 0, MB8, Wq);
        gemm2_kernel<MODE_RES, false, false, 64><<<dim3(64 * 12), blk, 0, stream>>>(
            hb, W2T, bf2, nullptr, nullptr, x1b, y2b, MSZ, D_, 1536, EXPD_, EXPD_, 0, MB8, Wq);
        gemm2_kernel<MODE_RES, false, false, 64><<<dim3(64 * 12), blk, 0, stream>>>(
            hb + 1536, W2T + 1536, nullptr, nullptr, nullptr, y2b, y2b, MSZ, D_, 1536, EXPD_, EXPD_, -1, MB8, Wq);
    } else if (tier == 1) {
        // N-split halves in hb = R2|R3 (V, y1 dead; hb contiguous stride 1536); y2 -> R4
        bf16* hb = R2;
        y2b = R4;
        gemm2_kernel<MODE_GELU, false, false, 128><<<dim3(64 * 12), blk, 0, stream>>>(
            x1b, W1T, bf1, nullptr, nullptr, nullptr, hb, MSZ, 1536, D_, D_, D_, 0, MB8, Wq);
        gemm2_kernel<MODE_RES, false, false, 64><<<dim3(64 * 12), blk, 0, stream>>>(
            hb, W2T, bf2, nullptr, nullptr, x1b, y2b, MSZ, D_, 1536, 1536, EXPD_, 0, MB8, Wq);
        gemm2_kernel<MODE_GELU, false, false, 128><<<dim3(64 * 12), blk, 0, stream>>>(
            x1b, W1T + (size_t)1536 * D_, bf1, nullptr, nullptr, nullptr, hb, MSZ, 1536, D_, D_, D_, 1536, MB8, Wq);
        gemm2_kernel<MODE_RES, false, false, 64><<<dim3(64 * 12), blk, 0, stream>>>(
            hb, W2T + 1536, nullptr, nullptr, nullptr, y2b, y2b, MSZ, D_, 1536, 1536, EXPD_, -1, MB8, Wq);
    } else {
        // 4-REG fallback: M-chunked FFN (hb = R3 after y1 consumed; y2 -> R2, V dead)
        bf16* hb = R3;
        y2b = R2;
        const int CH = 2048;   // 16 m-blocks -> mstripe 2
        for (int c0 = 0; c0 < MSZ; c0 += CH) {
            const bf16* x1c = x1b + (size_t)c0 * D_;
            gemm2_kernel<MODE_GELU, false, false, 128><<<dim3(16 * 24), blk, 0, stream>>>(
                x1c, W1T, bf1, nullptr, nullptr, nullptr, hb, CH, EXPD_, D_, D_, D_, 0, 2, Wq);
            gemm2_kernel<MODE_RES, false, false, 64><<<dim3(16 * 12), blk, 0, stream>>>(
                hb, W2T, bf2, nullptr, nullptr, x1c, y2b + (size_t)c0 * D_, CH, D_, EXPD_, EXPD_, EXPD_, 0, 2, Wq);
        }
    }

    // 9) out = LN2(y2) -> d_out
    ln_kernel<true><<<dim3(MSZ / 4), blk, 0, stream>>>(y2b, g2, be2, d_out, Wq);
}

// Round 12
// 458.552 us; speedup vs baseline: 1.0442x; 1.0442x over previous
//
#include <hip/hip_runtime.h>
#include <hip/hip_bf16.h>
#include <math.h>
#include <stdint.h>

// ---- problem constants ----
#define B_    4
#define S_    2048
#define D_    768
#define H_    8
#define HD_   96
#define EXPD_ 3072
#define MSZ   8192   // B*S

#define QSCALE 0.14724439f   // HD^-0.5 * log2(e), folded into Q at QKV epilogue
#define M0_    12.0f         // fixed softmax exponent offset

typedef __bf16 bf16;
typedef __bf16 bf16x4 __attribute__((ext_vector_type(4)));
typedef __bf16 bf16x8 __attribute__((ext_vector_type(8)));
typedef float  f32x4  __attribute__((ext_vector_type(4)));
typedef float  f32x16 __attribute__((ext_vector_type(16)));

typedef __attribute__((address_space(1))) const uint32_t gu32;
typedef __attribute__((address_space(3))) uint32_t lu32;

__device__ __forceinline__ void async_copy16(const void* g, void* l) {
    __builtin_amdgcn_global_load_lds((gu32*)g, (lu32*)l, 16, 0, 0);
}

__device__ __forceinline__ float gelu_f(float x) {
    float x3 = x * x * x;
    return 0.5f * x * (1.0f + tanhf(0.7978845608028654f * (x + 0.044715f * x3)));
}

// Runtime dtype sniff: f32 buffer read as bf16 at even indices yields random
// exponents -> some |v|>=1e3 among 64 samples w.p. ~1. bf16 weights never trip.
__device__ __forceinline__ bool sniff_f32(const void* p) {
    const bf16* pb = (const bf16*)p;
    float v = (float)pb[2 * (threadIdx.x & 63)];
    bool big = !(fabsf(v) < 1000.0f);
    return __any(big) != 0;
}

__device__ __forceinline__ float dynld(const void* p, size_t i, bool f32in) {
    return f32in ? ((const float*)p)[i] : (float)((const bf16*)p)[i];
}

// Cast src (sniffed f32/bf16) -> bf16, 8 el/thread.
__global__ __launch_bounds__(256) void cast_kernel(
    const void* __restrict__ src, bf16* __restrict__ dst)
{
    const bool f32in = sniff_f32(src);
    size_t i = ((size_t)blockIdx.x * 256 + threadIdx.x) * 8;
    if (f32in) {
        f32x4 a = *(const f32x4*)((const float*)src + i);
        f32x4 b = *(const f32x4*)((const float*)src + i + 4);
        bf16x8 r;
#pragma unroll
        for (int e = 0; e < 4; ++e) { r[e] = (bf16)a[e]; r[e + 4] = (bf16)b[e]; }
        *(bf16x8*)(dst + i) = r;
    } else {
        *(bf16x8*)(dst + i) = *(const bf16x8*)((const bf16*)src + i);
    }
}

#define MODE_QKV  0   // fused QKV: Q(*QSCALE),K -> [bh][S][HD]; V -> [bh][HD][S]
#define MODE_RES  1   // out bf16 = c + bias(if boff>=0) + res
#define MODE_GELU 2   // out bf16 = gelu(c + bias)

// 32x32x16-MFMA GEMM, BK=64 via dual stride-32 LDS panels (halves barrier
// pairs vs BK=32 without the bank-pathological 64-el row stride; padding is
// impossible under global_load_lds's contiguous-dest rule).
// C = A(MxK, row-stride lda) @ Bt(NxK, row-stride ldb)^T + bias[boff+n]
// (boff<0: none). Tile 128xBN, 4 waves. K must be a multiple of 64.
// XCD-aware 1-D grid decode (m fastest within per-XCD stripe).
template<int MODE, bool ADYN, bool RESDYN, int BN>
__global__ __launch_bounds__(256) void gemm2_kernel(
    const void* __restrict__ A, const bf16* __restrict__ Bt,
    const void* __restrict__ b0, const void* __restrict__ b1, const void* __restrict__ b2,
    const void* __restrict__ res, bf16* __restrict__ out,
    int M, int N, int K, int lda, int ldb, int boff, int mstripe,
    const void* __restrict__ sniffp)
{
    constexpr int WN   = BN / 2;
    constexpr int NJ32 = WN / 32;
    constexpr int BSZ  = BN * 32;
    __shared__ __align__(16) bf16 Sh[8192 + 2 * BSZ];  // As0|As1|Bs0|Bs1; C-stage reuses front
    bf16* Asp[2] = { Sh, Sh + 4096 };
    bf16* Bsp[2] = { Sh + 8192, Sh + 8192 + BSZ };

    const bool f32in = sniff_f32(sniffp);
    const int tid  = threadIdx.x;
    const int w    = tid >> 6;
    const int lane = tid & 63;
    const int l32  = lane & 31;
    const int kh   = lane >> 5;     // k-half within a 16-wide mfma step
    const int wr   = w >> 1, wc = w & 1;

    // XCD-aware block decode (m-fast within stripe)
    const int lin  = blockIdx.x;
    const int xcd  = lin & 7;
    const int q    = lin >> 3;
    const int nb   = q / mstripe;
    const int mbin = q - nb * mstripe;
    const int m0   = (xcd * mstripe + mbin) * 128;
    const int n0   = nb * BN;

    const int rsub = lane >> 2;
    const int cb8  = (lane & 3) * 8;

    f32x16 acc[2][NJ32];
#pragma unroll
    for (int i = 0; i < 2; ++i)
#pragma unroll
        for (int j = 0; j < NJ32; ++j)
#pragma unroll
            for (int e = 0; e < 16; ++e) acc[i][j][e] = 0.f;

    const bf16*  Abf = (const bf16*)A;
    const float* Af  = (const float*)A;

    for (int k0 = 0; k0 < K; k0 += 64) {
        __syncthreads();
        // A tile 128x64 -> As0 (k0..+31) + As1 (k0+32..+63)
#pragma unroll
        for (int half = 0; half < 2; ++half) {
            if (ADYN && f32in) {
#pragma unroll
                for (int a = 0; a < 2; ++a) {
                    int row = w * 32 + a * 16 + rsub;
                    const float* sp = Af + (size_t)(m0 + row) * lda + k0 + half * 32 + cb8;
                    f32x4 u0 = *(const f32x4*)sp;
                    f32x4 u1 = *(const f32x4*)(sp + 4);
                    bf16x8 v;
#pragma unroll
                    for (int e = 0; e < 4; ++e) { v[e] = (bf16)u0[e]; v[e + 4] = (bf16)u1[e]; }
                    *(bf16x8*)(&Asp[half][(size_t)(w * 32 + a * 16) * 32 + lane * 8]) = v;
                }
            } else {
#pragma unroll
                for (int a = 0; a < 2; ++a) {
                    int row = w * 32 + a * 16 + rsub;
                    async_copy16(Abf + (size_t)(m0 + row) * lda + k0 + half * 32 + cb8,
                                 &Asp[half][(w * 32 + a * 16) * 32]);
                }
            }
            // B tile BNx64 -> Bs0 + Bs1
#pragma unroll
            for (int a = 0; a < BN / 64; ++a) {
                int row = w * (BN / 4) + a * 16 + rsub;
                async_copy16(Bt + (size_t)(n0 + row) * ldb + k0 + half * 32 + cb8,
                             &Bsp[half][(w * (BN / 4) + a * 16) * 32]);
            }
        }
        __syncthreads();

#pragma unroll
        for (int hs = 0; hs < 2; ++hs) {
            bf16x8 af[2][2], bfv[NJ32][2];
#pragma unroll
            for (int i = 0; i < 2; ++i)
#pragma unroll
                for (int ks = 0; ks < 2; ++ks)
                    af[i][ks] = *(const bf16x8*)(&Asp[hs][(wr * 64 + i * 32 + l32) * 32 + ks * 16 + kh * 8]);
#pragma unroll
            for (int j = 0; j < NJ32; ++j)
#pragma unroll
                for (int ks = 0; ks < 2; ++ks)
                    bfv[j][ks] = *(const bf16x8*)(&Bsp[hs][(wc * WN + j * 32 + l32) * 32 + ks * 16 + kh * 8]);
#pragma unroll
            for (int i = 0; i < 2; ++i)
#pragma unroll
                for (int j = 0; j < NJ32; ++j)
#pragma unroll
                    for (int ks = 0; ks < 2; ++ks)
                        acc[i][j] = __builtin_amdgcn_mfma_f32_32x32x16_bf16(af[i][ks], bfv[j][ks], acc[i][j], 0, 0, 0);
        }
    }

    if constexpr (MODE == MODE_QKV) {
        // scatter epilogue (scalar; layout non-contiguous by design)
#pragma unroll
        for (int j = 0; j < NJ32; ++j) {
            int nbase = n0 + wc * WN + j * 32;      // multiple of 32
            int which = nbase / D_;                 // wave-uniform
            int n2b   = nbase - which * D_;
            int h     = n2b / HD_;                  // wave-uniform (32 | 96)
            int hd0   = n2b - h * HD_;
            const void* bp = which == 0 ? b0 : (which == 1 ? b1 : b2);
            float bval = dynld(bp, n2b + l32, f32in);
            int hd = hd0 + l32;
#pragma unroll
            for (int i = 0; i < 2; ++i) {
#pragma unroll
                for (int g = 0; g < 16; ++g) {
                    int rr = (g & 3) + 8 * (g >> 2) + 4 * kh;
                    int m  = m0 + wr * 64 + i * 32 + rr;
                    float v = acc[i][j][g] + bval;
                    int b  = m >> 11;
                    int ss = m & (S_ - 1);
                    int bh = b * H_ + h;
                    if (which == 0) v *= QSCALE;
                    size_t dst;
                    if (which < 2)
                        dst = (size_t)which * (MSZ * D_) + ((size_t)bh * S_ + ss) * HD_ + hd;
                    else
                        dst = (size_t)2 * (MSZ * D_) + ((size_t)bh * HD_ + hd) * S_ + ss;
                    out[dst] = (bf16)v;
                }
            }
        }
    } else {
        // dense epilogue: stage C through LDS, emit b128 loads/stores.
        __syncthreads();                 // all waves done reading panels
        bf16* Cw = Sh + w * 2048;        // per-wave 64 x 32 slice
        for (int j = 0; j < NJ32; ++j) {
            int nl = n0 + wc * WN + j * 32 + l32;
            float bval = boff >= 0 ? dynld(b0, boff + nl, f32in) : 0.f;
#pragma unroll
            for (int i = 0; i < 2; ++i)
#pragma unroll
                for (int g = 0; g < 16; ++g) {
                    int rr = (g & 3) + 8 * (g >> 2) + 4 * kh;
                    float v = acc[i][j][g] + bval;
                    if constexpr (MODE == MODE_GELU) v = gelu_f(v);
                    Cw[(i * 32 + rr) * 32 + l32] = (bf16)v;
                }
            // same-wave LDS ops are in-order: reads below see the writes above
#pragma unroll
            for (int pass = 0; pass < 4; ++pass) {
                int row = pass * 16 + (lane >> 2);
                int cc  = (lane & 3) * 8;
                bf16x8 cv = *(const bf16x8*)&Cw[row * 32 + cc];
                int m = m0 + wr * 64 + row;
                int n = n0 + wc * WN + j * 32 + cc;
                size_t off = (size_t)m * N + n;
                if constexpr (MODE == MODE_RES) {
                    bf16x8 o;
                    if (RESDYN && f32in) {
                        f32x4 r0 = *(const f32x4*)((const float*)res + off);
                        f32x4 r1 = *(const f32x4*)((const float*)res + off + 4);
#pragma unroll
                        for (int e = 0; e < 4; ++e) {
                            o[e]     = (bf16)((float)cv[e] + r0[e]);
                            o[e + 4] = (bf16)((float)cv[e + 4] + r1[e]);
                        }
                    } else {
                        bf16x8 rv = *(const bf16x8*)((const bf16*)res + off);
#pragma unroll
                        for (int e = 0; e < 8; ++e) o[e] = (bf16)((float)cv[e] + (float)rv[e]);
                    }
                    *(bf16x8*)&out[off] = o;
                } else {
                    *(bf16x8*)&out[off] = cv;
                }
            }
        }
    }
}

// Flash attention: 512 threads (8 waves), Q-tile 128 (16 q-rows/wave),
// KV-tile 64, fixed-max softmax. Q,K: [bh][S][96]; Vt_g: [bh][96][S].
// grid (B*H, S/128): x = bh -> XCD k owns bh === k (mod 8) -> K/V L2 locality.
__global__ __launch_bounds__(512, 6) void flash_kernel(
    const bf16* __restrict__ Q, const bf16* __restrict__ Kk,
    const bf16* __restrict__ Vt_g, bf16* __restrict__ ctx)
{
    __shared__ __align__(16) bf16 Ks[64][104];
    __shared__ __align__(16) bf16 Vs[96][72];
    __shared__ __align__(16) bf16 Ps[8][16][72];  // per-wave P [q][kv]

    const int tid  = threadIdx.x;
    const int w    = tid >> 6;
    const int lane = tid & 63;
    const int quad = lane >> 4;
    const int l16  = lane & 15;
    const int bh   = blockIdx.x;
    const size_t base = (size_t)bh * S_ * HD_;
    const int q0   = blockIdx.y * 128 + w * 16;

    bf16x8 qf[3];
#pragma unroll
    for (int ch = 0; ch < 3; ++ch)
        qf[ch] = *(const bf16x8*)(Q + base + (size_t)(q0 + l16) * HD_ + ch * 32 + quad * 8);

    f32x4 oacc[6];
#pragma unroll
    for (int c = 0; c < 6; ++c) oacc[c] = (f32x4){0.f, 0.f, 0.f, 0.f};
    float lsum[4] = {0.f, 0.f, 0.f, 0.f};

    // division-free staging maps (512 threads)
    const int kvi  = tid & 255;
    const int ch2  = tid >> 8;                 // 0,1
    const int krow = kvi >> 2, kc8 = (kvi & 3) * 8 + ch2 * 32;
    const int vrow = (kvi >> 3) + ch2 * 32, vcb = (kvi & 7) * 8;
    const int krow2 = tid >> 2, kc82 = (tid & 3) * 8 + 64;   // tid<256
    const int vrow2 = (tid >> 3) + 64, vcb2 = (tid & 7) * 8; // tid<256

    for (int kv0 = 0; kv0 < S_; kv0 += 64) {
        __syncthreads();
        *(bf16x8*)(&Ks[krow][kc8]) =
            *(const bf16x8*)(Kk + base + (size_t)(kv0 + krow) * HD_ + kc8);
        *(bf16x8*)(&Vs[vrow][vcb]) =
            *(const bf16x8*)(Vt_g + base + (size_t)vrow * S_ + kv0 + vcb);
        if (tid < 256) {
            *(bf16x8*)(&Ks[krow2][kc82]) =
                *(const bf16x8*)(Kk + base + (size_t)(kv0 + krow2) * HD_ + kc82);
            *(bf16x8*)(&Vs[vrow2][vcb2]) =
                *(const bf16x8*)(Vt_g + base + (size_t)vrow2 * S_ + kv0 + vcb2);
        }
        __syncthreads();

        // S = (Q*QSCALE) K^T : four 16x16 kv-tiles
        f32x4 sacc[4];
#pragma unroll
        for (int t = 0; t < 4; ++t) {
            sacc[t] = (f32x4){0.f, 0.f, 0.f, 0.f};
#pragma unroll
            for (int ch = 0; ch < 3; ++ch) {
                bf16x8 kf = *(const bf16x8*)(&Ks[t * 16 + l16][ch * 32 + quad * 8]);
                sacc[t] = __builtin_amdgcn_mfma_f32_16x16x32_bf16(qf[ch], kf, sacc[t], 0, 0, 0);
            }
        }

        // fixed-max softmax: p = 2^(sacc - M0); per-lane partial row sums only
#pragma unroll
        for (int r = 0; r < 4; ++r) {
            int qr = quad * 4 + r;
            float p0 = exp2f(sacc[0][r] - M0_);
            float p1 = exp2f(sacc[1][r] - M0_);
            float p2 = exp2f(sacc[2][r] - M0_);
            float p3 = exp2f(sacc[3][r] - M0_);
            lsum[r] += (p0 + p1) + (p2 + p3);
            Ps[w][qr][l16]      = (bf16)p0;
            Ps[w][qr][16 + l16] = (bf16)p1;
            Ps[w][qr][32 + l16] = (bf16)p2;
            Ps[w][qr][48 + l16] = (bf16)p3;
        }
        // no barrier: Ps is per-wave (in-wave lgkmcnt ordering suffices)

        bf16x8 pf0 = *(const bf16x8*)(&Ps[w][l16][quad * 8]);
        bf16x8 pf1 = *(const bf16x8*)(&Ps[w][l16][32 + quad * 8]);
#pragma unroll
        for (int c = 0; c < 6; ++c) {
            bf16x8 vf0 = *(const bf16x8*)(&Vs[c * 16 + l16][quad * 8]);
            bf16x8 vf1 = *(const bf16x8*)(&Vs[c * 16 + l16][32 + quad * 8]);
            oacc[c] = __builtin_amdgcn_mfma_f32_16x16x32_bf16(pf0, vf0, oacc[c], 0, 0, 0);
            oacc[c] = __builtin_amdgcn_mfma_f32_16x16x32_bf16(pf1, vf1, oacc[c], 0, 0, 0);
        }
    }

#pragma unroll
    for (int r = 0; r < 4; ++r)
#pragma unroll
        for (int off = 1; off < 16; off <<= 1)
            lsum[r] += __shfl_xor(lsum[r], off);

    const int b = bh >> 3, h = bh & 7;
#pragma unroll
    for (int r = 0; r < 4; ++r) {
        float inv = 1.0f / lsum[r];
        int srow = q0 + quad * 4 + r;
        size_t rowbase = ((size_t)b * S_ + srow) * D_ + h * HD_;
#pragma unroll
        for (int c = 0; c < 6; ++c)
            ctx[rowbase + c * 16 + l16] = (bf16)(oacc[c][r] * inv);
    }
}

// LayerNorm over D=768: one wave per row (12 el/lane, bf16x4 vector I/O).
template<bool OUTDYN>
__global__ __launch_bounds__(256) void ln_kernel(
    const bf16* __restrict__ in, const void* __restrict__ g, const void* __restrict__ be,
    void* __restrict__ out, const void* __restrict__ sniffp)
{
    const bool f32in = sniff_f32(sniffp);
    const int w = threadIdx.x >> 6, lane = threadIdx.x & 63;
    const int row = blockIdx.x * 4 + w;
    const size_t rbase = (size_t)row * D_ + lane * 12;

    float v[12];
#pragma unroll
    for (int j = 0; j < 3; ++j) {
        bf16x4 t = *(const bf16x4*)(in + rbase + j * 4);
#pragma unroll
        for (int e = 0; e < 4; ++e) v[j * 4 + e] = (float)t[e];
    }
    float sum = 0.f;
#pragma unroll
    for (int j = 0; j < 12; ++j) sum += v[j];
#pragma unroll
    for (int off = 1; off < 64; off <<= 1) sum += __shfl_xor(sum, off);
    float mu = sum * (1.0f / D_);
    float sq = 0.f;
#pragma unroll
    for (int j = 0; j < 12; ++j) { v[j] -= mu; sq += v[j] * v[j]; }
#pragma unroll
    for (int off = 1; off < 64; off <<= 1) sq += __shfl_xor(sq, off);
    float rstd = rsqrtf(sq * (1.0f / D_) + 1e-5f);

    if (OUTDYN && f32in) {
        float* op = (float*)out + rbase;
#pragma unroll
        for (int j = 0; j < 3; ++j) {
            f32x4 t;
#pragma unroll
            for (int e = 0; e < 4; ++e) {
                int c = lane * 12 + j * 4 + e;
                t[e] = v[j * 4 + e] * rstd * dynld(g, c, true) + dynld(be, c, true);
            }
            *(f32x4*)(op + j * 4) = t;
        }
    } else {
        bf16* op = (bf16*)out + rbase;
#pragma unroll
        for (int j = 0; j < 3; ++j) {
            bf16x4 t;
#pragma unroll
            for (int e = 0; e < 4; ++e) {
                int c = lane * 12 + j * 4 + e;
                t[e] = (bf16)(v[j * 4 + e] * rstd * dynld(g, c, f32in) + dynld(be, c, f32in));
            }
            *(bf16x4*)(op + j * 4) = t;
        }
    }
}

// Transpose 64x64 tile helper
__device__ __forceinline__ void transpose_tile(
    const void* __restrict__ src, bf16* __restrict__ dst, int R, int C,
    int r0, int c0, bool f32in)
{
    __shared__ bf16 t[64][65];
    const int tx = threadIdx.x & 63, ty = threadIdx.x >> 6;
#pragma unroll
    for (int i = 0; i < 16; ++i) {
        int rr = ty + i * 4;
        t[rr][tx] = (bf16)dynld(src, (size_t)(r0 + rr) * C + c0 + tx, f32in);
    }
    __syncthreads();
#pragma unroll
    for (int i = 0; i < 16; ++i) {
        int cc = ty + i * 4;
        dst[(size_t)(c0 + cc) * R + r0 + tx] = t[tx][cc];
    }
}

// Wq/Wk/Wv (all 768x768) -> dst + z*D*D, one launch, grid (12,12,3)
__global__ __launch_bounds__(256) void transpose_qkv_kernel(
    const void* __restrict__ s0, const void* __restrict__ s1, const void* __restrict__ s2,
    bf16* __restrict__ dst)
{
    const void* src = blockIdx.z == 0 ? s0 : (blockIdx.z == 1 ? s1 : s2);
    const bool f32in = sniff_f32(src);
    transpose_tile(src, dst + (size_t)blockIdx.z * D_ * D_, D_, D_,
                   blockIdx.y * 64, blockIdx.x * 64, f32in);
}

// Wo/W1/W2 -> WoT|W1T|W2T, packed 1-D grid of 1296 tiles (no idle blocks)
__global__ __launch_bounds__(256) void transpose_mlp_kernel(
    const void* __restrict__ s0, const void* __restrict__ s1, const void* __restrict__ s2,
    bf16* __restrict__ dst)
{
    int id = blockIdx.x;
    const void* src;
    int R, C, r, c;
    size_t off;
    if (id < 144)      { src = s0; R = D_;    C = D_;    off = 0;
                         r = id / 12;          c = id % 12; }
    else if (id < 720) { src = s1; R = D_;    C = EXPD_; off = (size_t)D_ * D_;
                         int i = id - 144;     r = i / 48; c = i % 48; }
    else               { src = s2; R = EXPD_; C = D_;    off = (size_t)D_ * D_ + (size_t)D_ * EXPD_;
                         int i = id - 720;     r = i / 12; c = i % 12; }
    const bool f32in = sniff_f32(src);
    transpose_tile(src, dst + off, R, C, r * 64, c * 64, f32in);
}

extern "C" void kernel_launch(void* const* d_in, const int* in_sizes, int n_in,
                              void* d_out, int out_size, void* d_ws, size_t ws_size,
                              hipStream_t stream)
{
    (void)in_sizes; (void)n_in; (void)out_size;
    const void* x   = d_in[0];
    const void* Wq  = d_in[1];
    const void* bq  = d_in[2];
    const void* Wk  = d_in[3];
    const void* bk  = d_in[4];
    const void* Wv  = d_in[5];
    const void* bv  = d_in[6];
    const void* Wo  = d_in[7];
    const void* bo  = d_in[8];
    const void* g1  = d_in[9];
    const void* be1 = d_in[10];
    const void* W1  = d_in[11];
    const void* bf1 = d_in[12];
    const void* W2  = d_in[13];
    const void* bf2 = d_in[14];
    const void* g2  = d_in[15];
    const void* be2 = d_in[16];

    const size_t REG = (size_t)MSZ * D_ * 2;  // 12.58 MB
    char* p = (char*)d_ws;
    bf16* R0 = (bf16*)p;             // Q     -> x1
    bf16* R1 = (bf16*)(p + REG);     // K     -> WoT|W1T|W2T (10.0 MB)
    bf16* R2 = (bf16*)(p + 2 * REG); // V^T   -> (nsplit: hb) / (tier0: y2)
    bf16* R3 = (bf16*)(p + 3 * REG); // y1    -> (tier3: y2) / (nsplit: hb hi) / (tier0: hb)
    bf16* R4 = (bf16*)(p + 4 * REG); // xb (tier>=1); nsplit: -> y2

    // tiers: 3 = 9 REG (full h at p+4..8, xb at p+8) | 1 = 5 REG (nsplit) | 0 = 4 REG
    int tier = 0;
    if      (ws_size >= 9 * REG) tier = 3;
    else if (ws_size >= 5 * REG) tier = 1;
    bf16* xb = tier == 3 ? (bf16*)(p + 8 * REG) : R4;

    bf16* qkvT = (bf16*)d_out;       // WqT|WkT|WvT (3.54 MB) before flash
    bf16* ctx  = (bf16*)d_out;
    dim3 blk(256);
    const int MB8 = MSZ / 128 / 8;   // mstripe for full-M GEMMs = 8

    // 0) cast x -> bf16
    if (tier >= 1) cast_kernel<<<dim3(MSZ * D_ / (256 * 8)), blk, 0, stream>>>(x, xb);

    // 1) transpose Wq/Wk/Wv -> qkvT [2304][768]
    transpose_qkv_kernel<<<dim3(12, 12, 3), blk, 0, stream>>>(Wq, Wk, Wv, qkvT);

    // 2) fused QKV GEMM -> Q*QSCALE(R0), K(R1), V^T(R2).  grid 64x18 = 1152
    if (tier >= 1)
        gemm2_kernel<MODE_QKV, false, false, 128><<<dim3(64 * 18), blk, 0, stream>>>(
            xb, qkvT, bq, bk, bv, nullptr, R0, MSZ, 2304, D_, D_, D_, 0, MB8, Wq);
    else
        gemm2_kernel<MODE_QKV, true, false, 128><<<dim3(64 * 18), blk, 0, stream>>>(
            x, qkvT, bq, bk, bv, nullptr, R0, MSZ, 2304, D_, D_, D_, 0, MB8, Wq);

    // 3) flash attention -> ctx (d_out; qkvT dead). grid x = bh (XCD locality).
    flash_kernel<<<dim3(B_ * H_, S_ / 128), dim3(512), 0, stream>>>(R0, R1, R2, ctx);

    // 4) transpose Wo/W1/W2 into R1 (K dead)
    bf16* WoT = R1;
    bf16* W1T = WoT + (size_t)D_ * D_;
    bf16* W2T = W1T + (size_t)D_ * EXPD_;
    transpose_mlp_kernel<<<dim3(1296), blk, 0, stream>>>(Wo, W1, W2, WoT);

    // 5) y1 = ctx@Wo + bo + x -> R3   (BN=64, grid 64x12 = 768)
    if (tier >= 1)
        gemm2_kernel<MODE_RES, false, false, 64><<<dim3(64 * 12), blk, 0, stream>>>(
            ctx, WoT, bo, nullptr, nullptr, xb, R3, MSZ, D_, D_, D_, D_, 0, MB8, Wq);
    else
        gemm2_kernel<MODE_RES, false, true, 64><<<dim3(64 * 12), blk, 0, stream>>>(
            ctx, WoT, bo, nullptr, nullptr, x, R3, MSZ, D_, D_, D_, D_, 0, MB8, Wq);

    // 6) x1 = LN1(y1) -> R0 (Q dead)
    bf16* x1b = R0;
    ln_kernel<false><<<dim3(MSZ / 4), blk, 0, stream>>>(R3, g1, be1, x1b, Wq);

    // 7/8) FFN -> y2
    bf16* y2b;
    if (tier == 3) {
        // full h (4 REG at p+4..8); single W1 + single W2 (lda = EXPD_)
        bf16* hb = R4;
        y2b = R3;   // y1 dead
        gemm2_kernel<MODE_GELU, false, false, 128><<<dim3(64 * 24), blk, 0, stream>>>(
            x1b, W1T, bf1, nullptr, nullptr, nullptr, hb, MSZ, EXPD_, D_, D_, D_, 0, MB8, Wq);
        gemm2_kernel<MODE_RES, false, false, 64><<<dim3(64 * 12), blk, 0, stream>>>(
            hb, W2T, bf2, nullptr, nullptr, x1b, y2b, MSZ, D_, EXPD_, EXPD_, EXPD_, 0, MB8, Wq);
    } else if (tier == 1) {
        // N-split halves in hb = R2|R3 (V, y1 dead; hb contiguous stride 1536); y2 -> R4
        bf16* hb = R2;
        y2b = R4;
        gemm2_kernel<MODE_GELU, false, false, 128><<<dim3(64 * 12), blk, 0, stream>>>(
            x1b, W1T, bf1, nullptr, nullptr, nullptr, hb, MSZ, 1536, D_, D_, D_, 0, MB8, Wq);
        gemm2_kernel<MODE_RES, false, false, 64><<<dim3(64 * 12), blk, 0, stream>>>(
            hb, W2T, bf2, nullptr, nullptr, x1b, y2b, MSZ, D_, 1536, 1536, EXPD_, 0, MB8, Wq);
        gemm2_kernel<MODE_GELU, false, false, 128><<<dim3(64 * 12), blk, 0, stream>>>(
            x1b, W1T + (size_t)1536 * D_, bf1, nullptr, nullptr, nullptr, hb, MSZ, 1536, D_, D_, D_, 1536, MB8, Wq);
        gemm2_kernel<MODE_RES, false, false, 64><<<dim3(64 * 12), blk, 0, stream>>>(
            hb, W2T + 1536, nullptr, nullptr, nullptr, y2b, y2b, MSZ, D_, 1536, 1536, EXPD_, -1, MB8, Wq);
    } else {
        // 4-REG fallback: M-chunked FFN (hb = R3 after y1 consumed; y2 -> R2, V dead)
        bf16* hb = R3;
        y2b = R2;
        const int CH = 2048;   // 16 m-blocks -> mstripe 2
        for (int c0 = 0; c0 < MSZ; c0 += CH) {
            const bf16* x1c = x1b + (size_t)c0 * D_;
            gemm2_kernel<MODE_GELU, false, false, 128><<<dim3(16 * 24), blk, 0, stream>>>(
                x1c, W1T, bf1, nullptr, nullptr, nullptr, hb, CH, EXPD_, D_, D_, D_, 0, 2, Wq);
            gemm2_kernel<MODE_RES, false, false, 64><<<dim3(16 * 12), blk, 0, stream>>>(
                hb, W2T, bf2, nullptr, nullptr, x1c, y2b + (size_t)c0 * D_, CH, D_, EXPD_, EXPD_, EXPD_, 0, 2, Wq);
        }
    }

    // 9) out = LN2(y2) -> d_out
    ln_kernel<true><<<dim3(MSZ / 4), blk, 0, stream>>>(y2b, g2, be2, d_out, Wq);
}